// Round 7
// baseline (280.131 us; speedup 1.0000x reference)
//
#include <hip/hip_runtime.h>
#include <cmath>

#define BB 4
#define TT 2048
#define CC 1024
#define HH 16
#define DD 64
#define MM (BB*TT)   // 8192

typedef _Float16 f16x8 __attribute__((ext_vector_type(8)));
typedef _Float16 f16x4 __attribute__((ext_vector_type(4)));
typedef _Float16 f16x2 __attribute__((ext_vector_type(2)));
typedef float f32x4 __attribute__((ext_vector_type(4)));
typedef unsigned short ushort_t;

// legacy K=16 f16 MFMA: spelled WITHOUT underscore before f16 (pre-gfx950
// naming; compiler fix-it verified R7)
#define MFMA16(a,b,c) __builtin_amdgcn_mfma_f32_16x16x16f16(a,b,c,0,0,0)

__device__ __forceinline__ unsigned short f2h(float f) {
    _Float16 h = (_Float16)f;
    return __builtin_bit_cast(unsigned short, h);
}

// packed f32x2 -> f16x2 (v_cvt_pkrtz_f16_f32); builtin returns __fp16x2,
// bit-cast to our _Float16x2 (identical layout)
__device__ __forceinline__ f16x2 cvt_pk(float a, float b) {
    return __builtin_bit_cast(f16x2, __builtin_amdgcn_cvt_pkrtz(a, b));
}

// async global->LDS, 16 bytes per lane. LDS dest is WAVE-UNIFORM base;
// HW adds lane*16.
__device__ __forceinline__ void gld16(const void* gsrc, void* ldst) {
    void* g = const_cast<void*>(gsrc);
    __builtin_amdgcn_global_load_lds(
        (__attribute__((address_space(1))) void*)g,
        (__attribute__((address_space(3))) void*)ldst,
        16, 0, 0);
}

// ---------------------------------------------------------------------------
// prep: fp32 -> f16 (packed x4)
// ---------------------------------------------------------------------------
__global__ __launch_bounds__(256)
void cvt4_kernel(const float* __restrict__ in, ushort_t* __restrict__ out, long n4) {
    long i = (long)blockIdx.x * blockDim.x + threadIdx.x;
    if (i >= n4) return;
    float4 v = ((const float4*)in)[i];
    ushort4 o;
    o.x = f2h(v.x); o.y = f2h(v.y); o.z = f2h(v.z); o.w = f2h(v.w);
    ((ushort4*)out)[i] = o;
}

// ---------------------------------------------------------------------------
// prep: transpose + convert: in[K][N] fp32 -> out[N][K] f16. 32x32 tiles.
// ---------------------------------------------------------------------------
__global__ __launch_bounds__(256)
void trcvt_kernel(const float* __restrict__ in, ushort_t* __restrict__ out,
                  int K, int N) {
    __shared__ float T[32][33];
    const int tx = threadIdx.x & 31;
    const int ty = threadIdx.x >> 5;
    const int n0 = blockIdx.x * 32;
    const int k0 = blockIdx.y * 32;
    #pragma unroll
    for (int i = 0; i < 4; ++i)
        T[ty + i * 8][tx] = in[(size_t)(k0 + ty + i * 8) * N + n0 + tx];
    __syncthreads();
    #pragma unroll
    for (int i = 0; i < 4; ++i)
        out[(size_t)(n0 + ty + i * 8) * K + k0 + tx] = f2h(T[tx][ty + i * 8]);
}

// ---------------------------------------------------------------------------
// f16 MFMA GEMM, R14: counted-vmcnt pipelined schedule (T3+T4) + st_16x32
// LDS XOR-swizzle (T2) + setprio (T5). The 2-barrier m97 structure is
// ceiling-bound by the vmcnt(0) drain at every __syncthreads (R13: halving
// barrier count bought ~nothing); this schedule never drains vmcnt to 0 in
// the main loop.
//   tile BM x 256, 512 thr = 8 waves (2m x 4n), wave = (BM/2) x 64, BK=32.
//   4 LDS K-tile slots (dyn LDS 4*(BM*64B + 16KB) = 128KB/96KB), stage-ahead-2.
//   iter kt: s_waitcnt vmcnt(batch) [drains batch kt, leaves kt+1 in flight]
//            -> raw s_barrier (publishes cross-wave gld16; no compiler drain)
//            -> stage kt+2 into slot (kt+2)&3 [its readers done at iter kt-2]
//            -> ds_read frags -> setprio(1) MFMAs setprio(0).
//   Last iter peeled with vmcnt(0). One barrier/iter bounds wave drift ->
//   slot rewrite (2 iters after last read) is race-free.
// Swizzle (rule #21: linear gld16 dest + inverse-swz global SOURCE + swz READ):
//   slot layout = [16row x 32col] subtiles (1024B); physical = logical ^
//   ((logical>>9 &1)<<5). Stage lane L covers physical L*16: logical
//   lsw = L*16 ^ (L>=32 ? 32 : 0) -> row lsw>>6, colh (lsw&63)>>1.
//   Read frag (row lrow, 16B chunk quad): half-off = (lrow*32+quad*8) ^
//   (lrow&8 ? 16 : 0). Kills the 8-way b128 column-read conflict (-> 4-pass
//   floor). Desk-checked roundtrip (row 9, col 5 -> phys byte 618 both sides).
// C[M,NN] = A[M,1024] @ B[1024,NN] + bias; QKV epilogue unchanged.
// ---------------------------------------------------------------------------
template<int BM, int NN, bool QKV>
__global__ __launch_bounds__(512, 2)
void hgemm2_kernel(const ushort_t* __restrict__ A, const ushort_t* __restrict__ Bt,
                   const float* __restrict__ bias, float* __restrict__ out,
                   ushort_t* __restrict__ qh, ushort_t* __restrict__ kh,
                   ushort_t* __restrict__ vh)
{
    constexpr int K    = 1024;
    constexpr int MT   = BM / 32;        // m-frags per wave (8 or 4)
    constexpr int AJ   = BM / 128;       // A gld16 per thread per K-tile (2 or 1)
    constexpr int AH   = BM * 32;        // A-slot halves
    constexpr int BH   = 256 * 32;       // B-slot halves
    constexpr int SLOT = AH + BH;        // halves per slot
    extern __shared__ ushort_t LDS[];    // 4 * SLOT halves

    const int tid  = threadIdx.x;
    const int lane = tid & 63;
    const int wid  = tid >> 6;           // 0..7
    const int wm   = wid >> 2;           // 0..1
    const int wn   = wid & 3;            // 0..3
    const int lrow = lane & 15;
    const int quad = lane >> 4;
    const int m0   = blockIdx.y * BM;
    const int n0   = blockIdx.x * 256;

    // staging geometry: physical within-subtile byte = lane*16; logical
    // flips byte-bit5 when lane>=32 (bit9 of lane*16).
    const int lsw   = (lane * 16) ^ ((lane & 32) ? 32 : 0);
    const int rowin = lsw >> 6;          // 0..15
    const int scolh = (lsw & 63) >> 1;   // 0,8,16,24 halves
    unsigned voffA[AJ], voffB[2];
    #pragma unroll
    for (int j = 0; j < AJ; ++j)
        voffA[j] = (unsigned)(m0 + (j * 8 + wid) * 16 + rowin) * K + scolh;
    #pragma unroll
    for (int j = 0; j < 2; ++j)
        voffB[j] = (unsigned)(n0 + (j * 8 + wid) * 16 + rowin) * K + scolh;
    const int ldsW = wid * 512;          // wave-uniform half-offset within 8KB chunk
    // read-side swizzled per-lane half offset within a subtile
    const int rdo = (lrow * 32 + quad * 8) ^ ((lrow & 8) ? 16 : 0);

    f32x4 acc[MT][4];
    const f32x4 z = {0.f, 0.f, 0.f, 0.f};
    #pragma unroll
    for (int mt = 0; mt < MT; ++mt)
        #pragma unroll
        for (int nt = 0; nt < 4; ++nt)
            acc[mt][nt] = z;

    auto STAGE = [&](int kt) {
        ushort_t* sb = &LDS[(kt & 3) * SLOT];
        #pragma unroll
        for (int j = 0; j < AJ; ++j)
            gld16(A + voffA[j] + kt * 32, sb + j * 4096 + ldsW);
        #pragma unroll
        for (int j = 0; j < 2; ++j)
            gld16(Bt + voffB[j] + kt * 32, sb + AH + j * 4096 + ldsW);
    };
    auto COMPUTE = [&](int kt) {
        const ushort_t* As = &LDS[(kt & 3) * SLOT];
        const ushort_t* Bs = As + AH;
        f16x8 af[MT], bf[4];
        #pragma unroll
        for (int mt = 0; mt < MT; ++mt)
            af[mt] = *(const f16x8*)&As[(wm * MT + mt) * 512 + rdo];
        #pragma unroll
        for (int nt = 0; nt < 4; ++nt)
            bf[nt] = *(const f16x8*)&Bs[(wn * 4 + nt) * 512 + rdo];
        __builtin_amdgcn_s_setprio(1);
        #pragma unroll
        for (int mt = 0; mt < MT; ++mt)
            #pragma unroll
            for (int nt = 0; nt < 4; ++nt)
                acc[mt][nt] = __builtin_amdgcn_mfma_f32_16x16x32_f16(
                    af[mt], bf[nt], acc[mt][nt], 0, 0, 0);
        __builtin_amdgcn_s_setprio(0);
    };

    STAGE(0);
    STAGE(1);
    for (int kt = 0; kt < 31; ++kt) {
        if constexpr (BM == 256)
            asm volatile("s_waitcnt vmcnt(4)" ::: "memory");
        else
            asm volatile("s_waitcnt vmcnt(3)" ::: "memory");
        __builtin_amdgcn_s_barrier();
        if (kt < 30) STAGE(kt + 2);
        COMPUTE(kt);
    }
    asm volatile("s_waitcnt vmcnt(0)" ::: "memory");
    __builtin_amdgcn_s_barrier();
    COMPUTE(31);

    #pragma unroll
    for (int mt = 0; mt < MT; ++mt) {
        const int rbase = m0 + wm * (BM / 2) + mt * 16 + quad * 4;
        #pragma unroll
        for (int nt = 0; nt < 4; ++nt) {
            const int col = n0 + wn * 64 + nt * 16 + lrow;
            const float bv = bias[col];
            if (QKV) {
                const int which = col >> 10;
                const int c = col & 1023;
                const int h = c >> 6, d = c & 63;
                const int b = rbase >> 11, t0 = rbase & 2047;
                if (which == 2) {
                    ushort4 pk;
                    pk.x = f2h(acc[mt][nt][0] + bv);
                    pk.y = f2h(acc[mt][nt][1] + bv);
                    pk.z = f2h(acc[mt][nt][2] + bv);
                    pk.w = f2h(acc[mt][nt][3] + bv);
                    *(ushort4*)&vh[(((size_t)b * HH + h) * DD + d) * TT + t0] = pk;
                } else {
                    ushort_t* dst = which ? kh : qh;
                    // q carries score-scale 8 and log2(e) for exp2-domain softmax
                    const float sc = which ? 1.0f : 8.0f * 1.44269504088896f;
                    #pragma unroll
                    for (int r = 0; r < 4; ++r)
                        dst[(((size_t)b * HH + h) * TT + t0 + r) * DD + d] =
                            f2h((acc[mt][nt][r] + bv) * sc);
                }
            } else {
                #pragma unroll
                for (int r = 0; r < 4; ++r)
                    out[(size_t)(rbase + r) * NN + col] = acc[mt][nt][r] + bv;
            }
        }
    }
}

// ---------------------------------------------------------------------------
// MFMA flash attention, R12 structure (unchanged; measured 95us, Occ 35.6,
// VALU 60, Mfma 23, zero spill): balanced-pair schedule + softmax micro-opts
// + double-buffered LDS (one barrier per iteration). Grid 16x64 = 1024 equal
// blocks, all co-resident (4/CU, LDS 36.9KB, lb(256,4)).
// ---------------------------------------------------------------------------
__global__ __launch_bounds__(256, 4)
void attn_mfma_kernel(const ushort_t* __restrict__ qh, const ushort_t* __restrict__ kh,
                      const ushort_t* __restrict__ vh, ushort_t* __restrict__ yh)
{
    __shared__ ushort_t Ks[2][64 * 72];   // [buf][key][d]
    __shared__ ushort_t Vs[2][64 * 72];   // [buf][d][key] (V transposed)

    const int pr   = blockIdx.x;          // pair index 0..15
    const int bh   = blockIdx.y;
    const int qtA  = 31 - pr;             // big tile first
    const int qtB  = pr;
    const int tid  = threadIdx.x;
    const int lane = tid & 63;
    const int w    = tid >> 6;
    const int lrow = lane & 15;
    const int quad = lane >> 4;

    const ushort_t* qbase = qh + (size_t)bh * TT * DD;
    const ushort_t* kbase = kh + (size_t)bh * TT * DD;
    const ushort_t* vbase = vh + (size_t)bh * DD * TT;
    const int b = bh >> 4, h = bh & 15;

    // staging: 256 threads x (2 K + 2 V) uint4; row ur/ur+32, 16B chunk uc
    const int ur = tid >> 3;            // 0..31
    const int uc = (tid & 7) * 8;       // halves

    int q0w = qtA * 64 + w * 16;
    f16x8 aq0 = *(const f16x8*)&qbase[(size_t)(q0w + lrow) * DD + quad * 8];
    f16x8 aq1 = *(const f16x8*)&qbase[(size_t)(q0w + lrow) * DD + 32 + quad * 8];

    const f32x4 z = {0.f, 0.f, 0.f, 0.f};
    f32x4 o[4] = {z, z, z, z};
    float mi = -1e30f, li = 0.f;

    // tile 0 regs
    uint4 kr0 = *(const uint4*)&kbase[(size_t)ur * DD + uc];
    uint4 kr1 = *(const uint4*)&kbase[(size_t)(ur + 32) * DD + uc];
    uint4 vr0 = *(const uint4*)&vbase[(size_t)ur * TT + uc];
    uint4 vr1 = *(const uint4*)&vbase[(size_t)(ur + 32) * TT + uc];

    // prologue: publish tile 0 into buf0, prefetch tile for i=1
    *(uint4*)&Ks[0][(ur)      * 72 + uc] = kr0;
    *(uint4*)&Ks[0][(ur + 32) * 72 + uc] = kr1;
    *(uint4*)&Vs[0][(ur)      * 72 + uc] = vr0;
    *(uint4*)&Vs[0][(ur + 32) * 72 + uc] = vr1;
    {
        const int nkt = (1 <= qtA) ? 1 : 0;   // i=1 -> phase A k-tile 1, or B k-tile 0
        const int nb  = nkt * 64;
        kr0 = *(const uint4*)&kbase[(size_t)(nb + ur) * DD + uc];
        kr1 = *(const uint4*)&kbase[(size_t)(nb + ur + 32) * DD + uc];
        vr0 = *(const uint4*)&vbase[(size_t)ur * TT + nb + uc];
        vr1 = *(const uint4*)&vbase[(size_t)(ur + 32) * TT + nb + uc];
    }
    __syncthreads();

    for (int i = 0; i <= 32; ++i) {
        const int cur = i & 1;
        if (i == qtA + 1) {
            // flush phase-A output; reset state for phase B
            #pragma unroll
            for (int r = 0; r < 4; ++r) {
                const float inv = 1.0f / __shfl(li, quad * 4 + r, 64);
                const int t = q0w + quad * 4 + r;
                #pragma unroll
                for (int dt = 0; dt < 4; ++dt)
                    yh[((size_t)b * TT + t) * CC + h * 64 + dt * 16 + lrow] =
                        f2h(o[dt][r] * inv);
            }
            q0w = qtB * 64 + w * 16;
            aq0 = *(const f16x8*)&qbase[(size_t)(q0w + lrow) * DD + quad * 8];
            aq1 = *(const f16x8*)&qbase[(size_t)(q0w + lrow) * DD + 32 + quad * 8];
            #pragma unroll
            for (int dt = 0; dt < 4; ++dt) o[dt] = z;
            mi = -1e30f; li = 0.f;
        }
        const int kt = (i <= qtA) ? i : i - qtA - 1;

        // S^T = K Q^T : C[row=key=quad*4+r][col=q=lrow]
        f32x4 sv[4];
        __builtin_amdgcn_s_setprio(1);
        #pragma unroll
        for (int c = 0; c < 4; ++c) {
            f16x8 ka = *(const f16x8*)&Ks[cur][(c * 16 + lrow) * 72 + quad * 8];
            f16x8 kb = *(const f16x8*)&Ks[cur][(c * 16 + lrow) * 72 + 32 + quad * 8];
            sv[c] = __builtin_amdgcn_mfma_f32_16x16x32_f16(ka, aq0, z, 0, 0, 0);
            sv[c] = __builtin_amdgcn_mfma_f32_16x16x32_f16(kb, aq1, sv[c], 0, 0, 0);
        }
        __builtin_amdgcn_s_setprio(0);

        // softmax: each lane owns q-row qg; its 16 values are keys c*16+quad*4+r
        const int kt2 = kt * 64;
        const int qg  = q0w + lrow;
        const bool diag = (i == qtA) || (i == 32);
        if (diag) {
            #pragma unroll
            for (int c = 0; c < 4; ++c)
                #pragma unroll
                for (int r = 0; r < 4; ++r)
                    if (kt2 + c * 16 + quad * 4 + r > qg) sv[c][r] = -3e38f;
        }
        // tree max (dep depth 4)
        float mc[4];
        #pragma unroll
        for (int c = 0; c < 4; ++c)
            mc[c] = fmaxf(fmaxf(sv[c][0], sv[c][1]), fmaxf(sv[c][2], sv[c][3]));
        float m = fmaxf(fmaxf(mc[0], mc[1]), fmaxf(mc[2], mc[3]));
        m = fmaxf(m, __shfl_xor(m, 16, 64));
        m = fmaxf(m, __shfl_xor(m, 32, 64));

        // defer-max (T13): only rescale when the running max grew by >8
        if (__any(m > mi + 8.0f)) {
            const float mnew  = fmaxf(mi, m);
            const float alpha = exp2f(mi - mnew);
            mi = mnew;
            li *= alpha;
            #pragma unroll
            for (int r = 0; r < 4; ++r) {
                const float ar = __shfl(alpha, quad * 4 + r, 64);
                #pragma unroll
                for (int dt = 0; dt < 4; ++dt) o[dt][r] *= ar;
            }
        }

        f16x4 ap[4];
        float rc[4];
        #pragma unroll
        for (int c = 0; c < 4; ++c) {
            const float p0 = exp2f(sv[c][0] - mi);
            const float p1 = exp2f(sv[c][1] - mi);
            const float p2 = exp2f(sv[c][2] - mi);
            const float p3 = exp2f(sv[c][3] - mi);
            rc[c] = (p0 + p1) + (p2 + p3);
            const f16x2 lo = cvt_pk(p0, p1);
            const f16x2 hi = cvt_pk(p2, p3);
            ap[c][0] = lo[0]; ap[c][1] = lo[1]; ap[c][2] = hi[0]; ap[c][3] = hi[1];
        }
        float rs = (rc[0] + rc[1]) + (rc[2] + rc[3]);
        rs += __shfl_xor(rs, 16, 64);
        rs += __shfl_xor(rs, 32, 64);
        li += rs;

        // O += P V : P^T C-layout IS the 16x16x16 A-frag (lane: q=lrow,
        // key=quad*4+j). V B-frag from Vs[d][key]: b64 per (dt,c).
        __builtin_amdgcn_s_setprio(1);
        #pragma unroll
        for (int dt = 0; dt < 4; ++dt)
            #pragma unroll
            for (int c = 0; c < 4; ++c) {
                f16x4 vb = *(const f16x4*)&Vs[cur][(dt * 16 + lrow) * 72 + c * 16 + quad * 4];
                o[dt] = MFMA16(ap[c], vb, o[dt]);
            }
        __builtin_amdgcn_s_setprio(0);

        // publish tile i+1 into the other buffer; prefetch tile i+2
        if (i < 32) {
            const int nxt = cur ^ 1;
            *(uint4*)&Ks[nxt][(ur)      * 72 + uc] = kr0;
            *(uint4*)&Ks[nxt][(ur + 32) * 72 + uc] = kr1;
            *(uint4*)&Vs[nxt][(ur)      * 72 + uc] = vr0;
            *(uint4*)&Vs[nxt][(ur + 32) * 72 + uc] = vr1;
            if (i < 31) {
                const int ni  = i + 2;
                const int nkt = (ni <= qtA) ? ni : ni - qtA - 1;
                const int nb  = nkt * 64;
                kr0 = *(const uint4*)&kbase[(size_t)(nb + ur) * DD + uc];
                kr1 = *(const uint4*)&kbase[(size_t)(nb + ur + 32) * DD + uc];
                vr0 = *(const uint4*)&vbase[(size_t)ur * TT + nb + uc];
                vr1 = *(const uint4*)&vbase[(size_t)(ur + 32) * TT + nb + uc];
            }
        }
        __syncthreads();
    }

    // final writeout (phase B)
    #pragma unroll
    for (int r = 0; r < 4; ++r) {
        const float inv = 1.0f / __shfl(li, quad * 4 + r, 64);
        const int t = q0w + quad * 4 + r;
        #pragma unroll
        for (int dt = 0; dt < 4; ++dt)
            yh[((size_t)b * TT + t) * CC + h * 64 + dt * 16 + lrow] =
                f2h(o[dt][r] * inv);
    }
}

// ---------------------------------------------------------------------------
// ws layout (halves): qh | kh | vh (8.39M each) | xh 8.39M (yh aliases xh)
//                     | wat 3.15M | wpt 1.05M     ~ 75 MB
// ---------------------------------------------------------------------------
extern "C" void kernel_launch(void* const* d_in, const int* in_sizes, int n_in,
                              void* d_out, int out_size, void* d_ws, size_t ws_size,
                              hipStream_t stream) {
    const float* x      = (const float*)d_in[0];
    const float* w_attn = (const float*)d_in[1];
    const float* b_attn = (const float*)d_in[2];
    const float* w_proj = (const float*)d_in[3];
    const float* b_proj = (const float*)d_in[4];
    float* out = (float*)d_out;

    const size_t per = (size_t)BB * HH * TT * DD;      // 8,388,608
    ushort_t* qh  = (ushort_t*)d_ws;
    ushort_t* kh  = qh + per;
    ushort_t* vh  = kh + per;
    ushort_t* xh  = vh + per;
    ushort_t* yh  = xh;                                 // alias: xh dead after GEMM1
    ushort_t* wat = xh + (size_t)MM * CC;
    ushort_t* wpt = wat + (size_t)3 * CC * CC;

    cvt4_kernel<<<(MM * CC / 4 + 255) / 256, 256, 0, stream>>>(x, xh, MM * CC / 4);
    trcvt_kernel<<<dim3(3 * CC / 32, CC / 32), 256, 0, stream>>>(w_attn, wat, CC, 3 * CC);
    trcvt_kernel<<<dim3(CC / 32, CC / 32), 256, 0, stream>>>(w_proj, wpt, CC, CC);

    // GEMM1: 256x256 tiles, grid 12 x 32 = 384 blocks, dyn LDS 128KB
    hgemm2_kernel<256, 3 * CC, true>
        <<<dim3(3 * CC / 256, MM / 256), 512, 4 * (256 * 32 + 256 * 32) * 2, stream>>>(
        xh, wat, b_attn, nullptr, qh, kh, vh);

    // 16 balanced q-tile pairs (x) x 64 heads (y); 1024 equal blocks, 4/CU
    attn_mfma_kernel<<<dim3(16, BB * HH), 256, 0, stream>>>(qh, kh, vh, yh);

    // GEMM2: 128x256 tiles, grid 4 x 64 = 256 blocks (1/CU even), dyn LDS 96KB
    hgemm2_kernel<128, CC, false>
        <<<dim3(CC / 256, MM / 128), 512, 4 * (128 * 32 + 256 * 32) * 2, stream>>>(
        yh, wpt, b_proj, out, nullptr, nullptr, nullptr);
}